// Round 1
// baseline (91.431 us; speedup 1.0000x reference)
//
#include <hip/hip_runtime.h>

__global__ __launch_bounds__(256) void se3_apply_kernel(
    const float* __restrict__ ext,   // [B,4,4] row-major
    const float* __restrict__ se3,   // [N,6]  (tx,ty,tz, wx,wy,wz)
    const int*   __restrict__ idx,   // [B]
    float*       __restrict__ out,   // [B,4,4]
    int B)
{
    int b = blockIdx.x * blockDim.x + threadIdx.x;
    if (b >= B) return;

    // ---- gather log transform ----
    int j = idx[b];
    const float* w6 = se3 + (size_t)j * 6;
    float2 p0 = *reinterpret_cast<const float2*>(w6 + 0);
    float2 p1 = *reinterpret_cast<const float2*>(w6 + 2);
    float2 p2 = *reinterpret_cast<const float2*>(w6 + 4);
    float tx = p0.x, ty = p0.y, tz = p1.x;
    float x  = p1.y, y  = p2.x, z  = p2.y;

    // ---- se3 exp map coefficients (reference semantics: clip(dot, EPS)) ----
    float dot   = x*x + y*y + z*z;
    float t2    = fmaxf(dot, 1e-4f);
    float theta = sqrtf(t2);
    float inv   = 1.0f / theta;
    float s, c;
    sincosf(theta, &s, &c);
    float A  = s * inv;
    float Bc = (1.0f - c) * inv * inv;
    float Cc = (theta - s) * inv * inv * inv;

    // K^2 building blocks
    float xx = x*x, yy = y*y, zz = z*z;
    float xy = x*y, xz = x*z, yz = y*z;

    // R = I + A*K + Bc*K^2
    float R00 = 1.0f - Bc*(yy + zz);
    float R01 = -A*z + Bc*xy;
    float R02 =  A*y + Bc*xz;
    float R10 =  A*z + Bc*xy;
    float R11 = 1.0f - Bc*(xx + zz);
    float R12 = -A*x + Bc*yz;
    float R20 = -A*y + Bc*xz;
    float R21 =  A*x + Bc*yz;
    float R22 = 1.0f - Bc*(xx + yy);

    // V = I + Bc*K + Cc*K^2
    float V00 = 1.0f - Cc*(yy + zz);
    float V01 = -Bc*z + Cc*xy;
    float V02 =  Bc*y + Cc*xz;
    float V10 =  Bc*z + Cc*xy;
    float V11 = 1.0f - Cc*(xx + zz);
    float V12 = -Bc*x + Cc*yz;
    float V20 = -Bc*y + Cc*xz;
    float V21 =  Bc*x + Cc*yz;
    float V22 = 1.0f - Cc*(xx + yy);

    // T = V @ t
    float T0 = V00*tx + V01*ty + V02*tz;
    float T1 = V10*tx + V11*ty + V12*tz;
    float T2 = V20*tx + V21*ty + V22*tz;

    // ---- load extrinsics rows ----
    const float4* E = reinterpret_cast<const float4*>(ext + (size_t)b * 16);
    float4 e0 = E[0], e1 = E[1], e2 = E[2], e3 = E[3];

    // ---- out = [R|T; 0 0 0 1] @ E ----
    float4 o0, o1, o2;
    o0.x = R00*e0.x + R01*e1.x + R02*e2.x + T0*e3.x;
    o0.y = R00*e0.y + R01*e1.y + R02*e2.y + T0*e3.y;
    o0.z = R00*e0.z + R01*e1.z + R02*e2.z + T0*e3.z;
    o0.w = R00*e0.w + R01*e1.w + R02*e2.w + T0*e3.w;

    o1.x = R10*e0.x + R11*e1.x + R12*e2.x + T1*e3.x;
    o1.y = R10*e0.y + R11*e1.y + R12*e2.y + T1*e3.y;
    o1.z = R10*e0.z + R11*e1.z + R12*e2.z + T1*e3.z;
    o1.w = R10*e0.w + R11*e1.w + R12*e2.w + T1*e3.w;

    o2.x = R20*e0.x + R21*e1.x + R22*e2.x + T2*e3.x;
    o2.y = R20*e0.y + R21*e1.y + R22*e2.y + T2*e3.y;
    o2.z = R20*e0.z + R21*e1.z + R22*e2.z + T2*e3.z;
    o2.w = R20*e0.w + R21*e1.w + R22*e2.w + T2*e3.w;

    float4* O = reinterpret_cast<float4*>(out + (size_t)b * 16);
    O[0] = o0;
    O[1] = o1;
    O[2] = o2;
    O[3] = e3;   // bottom row of refinement is [0,0,0,1]
}

extern "C" void kernel_launch(void* const* d_in, const int* in_sizes, int n_in,
                              void* d_out, int out_size, void* d_ws, size_t ws_size,
                              hipStream_t stream) {
    const float* ext = (const float*)d_in[0];   // [B,4,4]
    const float* se3 = (const float*)d_in[1];   // [N,6]
    const int*   idx = (const int*)d_in[2];     // [B]
    float* out = (float*)d_out;

    int B = in_sizes[2];                        // number of batch elements
    int block = 256;
    int grid = (B + block - 1) / block;
    se3_apply_kernel<<<grid, block, 0, stream>>>(ext, se3, idx, out, B);
}